// Round 14
// baseline (76.972 us; speedup 1.0000x reference)
//
#include <hip/hip_runtime.h>
#include <math.h>

namespace {
constexpr int kD = 512;
constexpr float kBetaMin = 0.1f;
constexpr float kBetaMax = 20.0f;
constexpr float kTMax = 1.0f;
// Spectrum of A = M M^T / D + I: lambda_min >= 1 (Wishart PSD),
// lambda_max ~ 4.96 (MP edge 4 + I + TW fluctuation). Containing bounds:
constexpr float kLamMin = 1.0f;
constexpr float kLamMax = 5.2f;
constexpr float kLamMid = 0.5f * (kLamMin + kLamMax);   // 3.1
constexpr float kDelta = (kLamMax - kLamMin) * 0.5f;    // 2.1
// kSteps = 4 matvecs (degree-4 polynomial) — same polynomial as r14/r18;
// truncation unchanged. r19 evaluates it in the Krylov basis of
// Abar = A - 3.1 I (centered -> coefficient cancellation C~2, hand-traced).
constexpr int kSteps = 4;

// r19: ONE LLC exchange round (r14/r18 had 4; r18's exchange-impl tightening
// measured +0.9us vs r14 => per-round cost is latency-structural, so cut the
// ROUND COUNT). Y = sum_j y_j(s) * Abar^j b; y_j from the identical scalar
// Chebyshev recurrence per sample (registers). Member holds Abar and Abar^2
// row-slabs in LDS (Abar^2 from a tiny 512^3 GEMM prologue; A symmetric).
// Round 1 (local): build full B from x; K1=Abar*B, K2=Abar^2*B rows.
// Exchange: publish/gather full K2 only (16 KB/group).
// Round 2 (local): K3=Abar*K2, K4=Abar^2*K2 rows; combine, write out.
constexpr int kGroupsC = 32;     // groups (16 batch-columns each)
constexpr int kMembers = 8;      // blocks per group (64 A-rows each)
constexpr int kCPG = 16;         // columns per group
constexpr int kRowsB = 64;       // A-rows per block
constexpr int kBarStride = 4;    // uints per flag (16 B)
constexpr int kFragElems = kCPG * kD;   // 8192 bf16 = 16 KB per group block

typedef __attribute__((ext_vector_type(8))) short short8;   // 8 bf16
typedef __attribute__((ext_vector_type(4))) float float4v;  // 4 fp32 acc
}

__device__ inline unsigned short bf16_rne(float f) {
  unsigned u = __float_as_uint(f);
  u = (u + 0x7FFFu + ((u >> 16) & 1u)) >> 16;
  return (unsigned short)u;
}

__device__ inline unsigned pack_bf16_rne2(float a, float b) {
  unsigned ua = __float_as_uint(a), ub = __float_as_uint(b);
  ua = (ua + 0x7FFFu + ((ua >> 16) & 1u)) >> 16;
  ub = (ub + 0x7FFFu + ((ub >> 16) & 1u)) >> 16;
  return ua | (ub << 16);
}

__device__ inline float bf16_to_f(unsigned short u) {
  return __uint_as_float((unsigned)u << 16);
}

// Coherence-bypassing 8 B accessors (relaxed agent-scope atomics ->
// global_{load,store}_dwordx2 sc0 sc1 through to the Infinity Cache —
// proven pattern from r10/r11/r14/r18).
__device__ inline void store8_agent(void* p, unsigned lo, unsigned hi) {
  const unsigned long long v = (unsigned long long)lo | ((unsigned long long)hi << 32);
  __hip_atomic_store((unsigned long long*)p, v, __ATOMIC_RELAXED,
                     __HIP_MEMORY_SCOPE_AGENT);
}
__device__ inline unsigned long long load8_agent(const void* p) {
  return __hip_atomic_load((const unsigned long long*)p, __ATOMIC_RELAXED,
                           __HIP_MEMORY_SCOPE_AGENT);
}

// Prologue 1: Abar = A - 3.1 I -> bf16 row-major; zero the 4 KB flag region
// (per-iteration reset -> immune to workspace poison semantics).
__global__ __launch_bounds__(256) void a_to_bf16_zs(
    const float* __restrict__ A, unsigned* __restrict__ Abf,
    unsigned* __restrict__ flags) {
  const int g = blockIdx.x * 256 + threadIdx.x;  // 65536 threads
  const int row = g >> 7;                        // [0,512)
  const int colb = (g & 127) * 4;                // 4 consecutive cols
  float4 f = ((const float4*)A)[g];
  const int d = row - colb;
  if (d == 0) f.x -= kLamMid;
  else if (d == 1) f.y -= kLamMid;
  else if (d == 2) f.z -= kLamMid;
  else if (d == 3) f.w -= kLamMid;
  uint2 u;
  u.x = pack_bf16_rne2(f.x, f.y);
  u.y = pack_bf16_rne2(f.z, f.w);
  ((uint2*)Abf)[g] = u;
  if (blockIdx.x == 0) {
#pragma unroll
    for (int q = 0; q < 4; ++q)
      flags[q * 256 + threadIdx.x] = 0u;   // 1024 uints = 256 flags x 4 stride
  }
}

// Prologue 2: A2 = Abar * Abar (bf16 in, fp32 acc, bf16 out). A symmetric ->
// both operands read as ROWS of Abf. 256 blocks: 32 row-tiles(16) x 8
// col-tiles(64); 4 waves, wave w owns cols [C0+16w, C0+16w+16). All reads
// L2-resident (Abf = 512 KB).
__global__ __launch_bounds__(256) void a2_gemm(
    const unsigned short* __restrict__ Abf, unsigned short* __restrict__ A2bf) {
  const int rt = blockIdx.x & 31;
  const int ct = blockIdx.x >> 5;
  const int R0 = rt * 16, C0 = ct * 64;
  const int wave = threadIdx.x >> 6, lane = threadIdx.x & 63;
  const int colw = C0 + wave * 16;
  float4v acc = {0.f, 0.f, 0.f, 0.f};
  // A-frag: lane holds Abar[R0 + (lane&15)][kk*32 + (lane>>4)*8 ..+8]
  // B-frag: lane holds B[k][colw + (lane&15)] = Abar[colw+(lane&15)][k] (sym)
  const unsigned short* ar = Abf + (size_t)(R0 + (lane & 15)) * kD + (lane >> 4) * 8;
  const unsigned short* br = Abf + (size_t)(colw + (lane & 15)) * kD + (lane >> 4) * 8;
#pragma unroll
  for (int kk = 0; kk < kD / 32; ++kk) {
    const short8 af = *(const short8*)(ar + kk * 32);
    const short8 bf = *(const short8*)(br + kk * 32);
    acc = __builtin_amdgcn_mfma_f32_16x16x32_bf16(af, bf, acc, 0, 0, 0);
  }
  // C layout (m89-verified): col = lane&15, row = (lane>>4)*4 + m
#pragma unroll
  for (int m = 0; m < 4; ++m)
    A2bf[(size_t)(R0 + (lane >> 4) * 4 + m) * kD + colw + (lane & 15)] =
        bf16_rne(acc[m]);
}

// ---------------- One-exchange Krylov path (batch == 512) ----------------
// 256 blocks = 32 groups x 8 members; member m owns rows [64m,64m+64) of
// Abar AND Abar^2 (both fragment-ordered in LDS, 128 KB) -> 1 block/CU.
__global__ __launch_bounds__(256) void cheb_krylov(
    const float* __restrict__ x,    // [B, D]
    const float* __restrict__ t,    // [B]
    const float* __restrict__ mu,   // [D]
    const unsigned short* __restrict__ Abf,   // [D,D] bf16 Abar row-major
    const unsigned short* __restrict__ A2bf,  // [D,D] bf16 Abar^2 row-major
    float* __restrict__ out,        // [B, D]
    unsigned short* __restrict__ K2g,   // 32 x 16 KB fragment-ordered
    unsigned* __restrict__ flags) {     // 256 x 16 B, zeroed by prologue
  const int group = blockIdx.x & (kGroupsC - 1);
  const int member = blockIdx.x >> 5;
  const int c0 = group * kCPG;
  const int i0 = member * kRowsB;
  const int tid = threadIdx.x;
  const int wave = tid >> 6;
  const int lane = tid & 63;
  const int quad = lane >> 4;
  const int lc = lane & 15;
  const int c = c0 + lc;                        // this thread's batch column
  const int ibase = i0 + wave * 16 + quad * 4;  // 4 consecutive output rows

  // Fragment elem for (row k, col): ((k>>5)*64 + ((k>>3)&3)*16 + col)*8 + (k&7)
  const int locElem =
      ((ibase >> 5) * 64 + ((ibase >> 3) & 3) * 16 + lc) * 8 + (ibase & 7);
  const size_t fragOff = (size_t)group * kFragElems + (size_t)locElem;

  // LDS: Abar slab 64 KB + Abar^2 slab 64 KB + B/K2 buffer 16 KB = 144 KB
  __shared__ alignas(16) unsigned short As[kRowsB * kD];
  __shared__ alignas(16) unsigned short A2s[kRowsB * kD];
  __shared__ alignas(16) unsigned short Bs[kFragElems];

  // --- per-column scalars ---
  const float tb = t[c];
  const float Bt = (kBetaMax - kBetaMin) / (2.0f * kTMax) * tb * tb + kBetaMin * tb;
  const float s_c = expm1f(Bt);
  const float eh = expf(0.5f * Bt);
  const float oscale = -eh * sqrtf(1.0f - expf(-Bt));
  const float theta = kLamMid + s_c;            // = sigma-bar (M = Abar + theta I)
  const float two_sig1 = 2.0f * theta / kDelta;
  const float c2base = 2.0f / kDelta;

  // --- build FULL B (16 cols x 512 rows) into Bs, fragment order ---
  // thread: col = lc (== its compute column), rows (tid>>4)*32 .. +32
  {
    const int rb0 = (tid >> 4) * 32;
#pragma unroll
    for (int ch = 0; ch < 4; ++ch) {
      const int k0 = rb0 + ch * 8;
      const float4 xa = *(const float4*)(x + (size_t)c * kD + k0);
      const float4 xb = *(const float4*)(x + (size_t)c * kD + k0 + 4);
      const float4 ma = *(const float4*)(mu + k0);
      const float4 mb = *(const float4*)(mu + k0 + 4);
      uint4 u;
      u.x = pack_bf16_rne2(eh * xa.x - ma.x, eh * xa.y - ma.y);
      u.y = pack_bf16_rne2(eh * xa.z - ma.z, eh * xa.w - ma.w);
      u.z = pack_bf16_rne2(eh * xb.x - mb.x, eh * xb.y - mb.y);
      u.w = pack_bf16_rne2(eh * xb.z - mb.z, eh * xb.w - mb.w);
      const int e = ((k0 >> 5) * 64 + ((k0 >> 3) & 3) * 16 + lc) * 8;  // k0%8==0
      *(uint4*)&Bs[e] = u;
    }
  }

  // --- stage Abar + Abar^2 slabs (bf16, fragment reorder, coalesced reads) ---
  for (int idx = tid; idx < kRowsB * (kD / 8); idx += 256) {
    const int row = idx >> 6;              // local row 0..63
    const int col = (idx & 63) * 8;
    const int w = row >> 4, l = row & 15;
    const int kk = col >> 5, qd = (col >> 3) & 3;
    const int dst = (w * 1024 + kk * 64 + qd * 16 + l) * 8;
    const uint4 v1 = *(const uint4*)(Abf + (size_t)(i0 + row) * kD + col);
    *(uint4*)&As[dst] = v1;
    const uint4 v2 = *(const uint4*)(A2bf + (size_t)(i0 + row) * kD + col);
    *(uint4*)&A2s[dst] = v2;
  }
  __syncthreads();

  // --- round 1: K1 = Abar*B rows, K2 = Abar^2*B rows ---
  float4v k1 = {0.f, 0.f, 0.f, 0.f}, k2 = {0.f, 0.f, 0.f, 0.f};
  const unsigned short* afp = As + (size_t)(wave * 1024 + lane) * 8;
  const unsigned short* afp2 = A2s + (size_t)(wave * 1024 + lane) * 8;
#pragma unroll
  for (int kk = 0; kk < kD / 32; ++kk) {
    const short8 bfv = *(const short8*)(Bs + (size_t)(kk * 64 + lane) * 8);
    const short8 a1 = *(const short8*)(afp + (size_t)kk * 512);
    const short8 a2 = *(const short8*)(afp2 + (size_t)kk * 512);
    k1 = __builtin_amdgcn_mfma_f32_16x16x32_bf16(a1, bfv, k1, 0, 0, 0);
    k2 = __builtin_amdgcn_mfma_f32_16x16x32_bf16(a2, bfv, k2, 0, 0, 0);
  }

  // --- keep b rows (K0) in registers before Bs is overwritten by K2_full ---
  float bR[4];
  {
    const uint2 bu = *(const uint2*)&Bs[locElem];   // 4 consecutive elems
    bR[0] = bf16_to_f((unsigned short)(bu.x & 0xFFFFu));
    bR[1] = bf16_to_f((unsigned short)(bu.x >> 16));
    bR[2] = bf16_to_f((unsigned short)(bu.y & 0xFFFFu));
    bR[3] = bf16_to_f((unsigned short)(bu.y >> 16));
  }

  // --- publish K2 rows; single flag round ---
  store8_agent(K2g + fragOff, pack_bf16_rne2(k2[0], k2[1]),
               pack_bf16_rne2(k2[2], k2[3]));
  __syncthreads();   // drains vmcnt: whole block's K2 publish complete
  unsigned* const myFlag = flags + ((group << 3) + member) * kBarStride;
  if (tid == 0)
    __hip_atomic_store(myFlag, 1u, __ATOMIC_RELAXED, __HIP_MEMORY_SCOPE_AGENT);
  if (tid < kMembers) {
    const unsigned* fl = flags + ((group << 3) + tid) * kBarStride;
    while (__hip_atomic_load(fl, __ATOMIC_RELAXED, __HIP_MEMORY_SCOPE_AGENT) < 1u)
      __builtin_amdgcn_s_sleep(1);
  }
  __syncthreads();

  // --- gather FULL K2 into Bs (coalesced LLC loads) ---
  {
    const unsigned short* gin = K2g + (size_t)group * kFragElems;
    unsigned long long stg[8];
#pragma unroll
    for (int i = 0; i < 8; ++i)
      stg[i] = load8_agent((const char*)gin + (size_t)i * 2048 + (size_t)tid * 8);
#pragma unroll
    for (int i = 0; i < 8; ++i)
      *(unsigned long long*)((char*)Bs + (size_t)i * 2048 + (size_t)tid * 8) = stg[i];
  }
  __syncthreads();

  // --- round 2: K3 = Abar*K2 rows, K4 = Abar^2*K2 rows ---
  float4v k3 = {0.f, 0.f, 0.f, 0.f}, k4 = {0.f, 0.f, 0.f, 0.f};
#pragma unroll
  for (int kk = 0; kk < kD / 32; ++kk) {
    const short8 bfv = *(const short8*)(Bs + (size_t)(kk * 64 + lane) * 8);
    const short8 a1 = *(const short8*)(afp + (size_t)kk * 512);
    const short8 a2 = *(const short8*)(afp2 + (size_t)kk * 512);
    k3 = __builtin_amdgcn_mfma_f32_16x16x32_bf16(a1, bfv, k3, 0, 0, 0);
    k4 = __builtin_amdgcn_mfma_f32_16x16x32_bf16(a2, bfv, k4, 0, 0, 0);
  }

  // --- scalar Chebyshev recurrence on Krylov coefficients (fp32, exact
  //     same polynomial as r14/r18: D,R,Y as coeff 5-vectors over Abar^j b;
  //     M*V coeffs: m_j = d_{j-1} + theta*d_j) ---
  float d0 = 1.0f / theta, d1 = 0.f, d2 = 0.f, d3 = 0.f, d4 = 0.f;
  float r0 = 1.0f, r1 = 0.f, r2 = 0.f, r3 = 0.f, r4 = 0.f;
  float y0 = d0, y1 = 0.f, y2 = 0.f, y3 = 0.f, y4 = 0.f;
  float rp = kDelta / theta;   // 1/sigma1
#pragma unroll
  for (int k = 1; k <= kSteps; ++k) {
    const float rn = 1.0f / (two_sig1 - rp);
    const float cc1 = rn * rp;
    const float cc2 = rn * c2base;
    const float m0 = theta * d0;
    const float m1 = d0 + theta * d1;
    const float m2 = d1 + theta * d2;
    const float m3 = d2 + theta * d3;
    const float m4 = d3 + theta * d4;
    r0 -= m0; r1 -= m1; r2 -= m2; r3 -= m3; r4 -= m4;
    d0 = fmaf(cc1, d0, cc2 * r0);
    d1 = fmaf(cc1, d1, cc2 * r1);
    d2 = fmaf(cc1, d2, cc2 * r2);
    d3 = fmaf(cc1, d3, cc2 * r3);
    d4 = fmaf(cc1, d4, cc2 * r4);
    y0 += d0; y1 += d1; y2 += d2; y3 += d3; y4 += d4;
    rp = rn;
  }

  // --- combine and write ---
  float4 o;
  o.x = oscale * (y0 * bR[0] + y1 * k1[0] + y2 * k2[0] + y3 * k3[0] + y4 * k4[0]);
  o.y = oscale * (y0 * bR[1] + y1 * k1[1] + y2 * k2[1] + y3 * k3[1] + y4 * k4[1]);
  o.z = oscale * (y0 * bR[2] + y1 * k1[2] + y2 * k2[2] + y3 * k3[2] + y4 * k4[2]);
  o.w = oscale * (y0 * bR[3] + y1 * k1[3] + y2 * k2[3] + y3 * k3[3] + y4 * k4[3]);
  *(float4*)(out + (size_t)c * kD + ibase) = o;
}

// ---------------- Fallback path (r6 kernel, any batch) ----------------
__global__ __launch_bounds__(256) void a_to_bf16(
    const float* __restrict__ A, unsigned* __restrict__ Abf) {
  const int i = blockIdx.x * 256 + threadIdx.x;
  const float4 f = ((const float4*)A)[i];
  uint2 u;
  u.x = pack_bf16_rne2(f.x, f.y);
  u.y = pack_bf16_rne2(f.z, f.w);
  ((uint2*)Abf)[i] = u;
}

namespace {
constexpr int fGroups = 8;
constexpr int fTPG = 128;
constexpr int fThreads = fGroups * fTPG;
constexpr int fRowsG = kD / fGroups;
constexpr int fG = 2;
constexpr int fDeg = 8;
constexpr int fRows = 8;
}

__global__ __launch_bounds__(fThreads) void vp_sde_cheb_fb(
    const float* __restrict__ x, const float* __restrict__ t,
    const float* __restrict__ mu, const uint2* __restrict__ Abf,
    float* __restrict__ out, int batch) {
  const int b0 = blockIdx.x * fG;
  const int tid = threadIdx.x;
  const int grp = tid >> 7;
  const int tl = tid & (fTPG - 1);
  const int d0 = 4 * tl;
  const int jbase = grp * fRowsG;

  __shared__ alignas(16) float d_sh[fG][kD];
  __shared__ alignas(16) float red_sh[fGroups - 1][fG][kD];

  float s[fG], two_sig1[fG], rho_prev[fG], oscale[fG];
  bool vld[fG];
  float4 y[fG], r[fG], dv[fG];
  const float two_over_delta = 2.0f / kDelta;

  uint2 buf0[fRows], buf1[fRows];
#pragma unroll
  for (int rr = 0; rr < fRows; ++rr)
    buf0[rr] = Abf[(size_t)(jbase + rr) * (kD / 4) + tl];

#pragma unroll
  for (int g = 0; g < fG; ++g) {
    const int b = b0 + g;
    vld[g] = (b < batch);
    const float tb = vld[g] ? t[b] : 1.0f;
    const float Bt = (kBetaMax - kBetaMin) / (2.0f * kTMax) * tb * tb + kBetaMin * tb;
    const float sg = expm1f(Bt);
    const float eh = expf(0.5f * Bt);
    s[g] = sg;
    oscale[g] = -eh * sqrtf(1.0f - expf(-Bt));
    const float theta = 0.5f * (kLamMin + kLamMax) + sg;
    const float sig1 = theta / kDelta;
    two_sig1[g] = 2.0f * sig1;
    rho_prev[g] = 1.0f / sig1;

    if (grp == 0) {
      float4 rv = {0.f, 0.f, 0.f, 0.f};
      if (vld[g]) {
        const float4 xv = *(const float4*)&x[(size_t)b * kD + d0];
        const float4 mu4 = *(const float4*)&mu[d0];
        rv.x = eh * xv.x - mu4.x;
        rv.y = eh * xv.y - mu4.y;
        rv.z = eh * xv.z - mu4.z;
        rv.w = eh * xv.w - mu4.w;
      }
      r[g] = rv;
      const float it = 1.0f / theta;
      dv[g].x = rv.x * it; dv[g].y = rv.y * it;
      dv[g].z = rv.z * it; dv[g].w = rv.w * it;
      y[g] = dv[g];
      *(float4*)&d_sh[g][d0] = dv[g];
    }
  }
  __syncthreads();

  for (int k = 1; k < fDeg; ++k) {
    float4 acc[fG];
#pragma unroll
    for (int g = 0; g < fG; ++g) acc[g] = {0.f, 0.f, 0.f, 0.f};

    auto stage = [&](uint2 (&cons)[fRows], uint2 (&ld)[fRows], int jc, int jl) {
#pragma unroll
      for (int rr = 0; rr < fRows; ++rr)
        ld[rr] = Abf[(size_t)(jbase + ((jl + rr) & (fRowsG - 1))) * (kD / 4) + tl];
      float4 pv[fG][fRows / 4];
#pragma unroll
      for (int g = 0; g < fG; ++g)
#pragma unroll
        for (int q = 0; q < fRows / 4; ++q)
          pv[g][q] = *(const float4*)&d_sh[g][jbase + jc + 4 * q];
#pragma unroll
      for (int q = 0; q < fRows / 4; ++q)
#pragma unroll
        for (int cc = 0; cc < 4; ++cc) {
          const uint2 u = cons[4 * q + cc];
          const float fa = __uint_as_float(u.x << 16);
          const float fb = __uint_as_float(u.x & 0xFFFF0000u);
          const float fc = __uint_as_float(u.y << 16);
          const float fd = __uint_as_float(u.y & 0xFFFF0000u);
#pragma unroll
          for (int g = 0; g < fG; ++g) {
            const float pj = (cc == 0) ? pv[g][q].x
                           : (cc == 1) ? pv[g][q].y
                           : (cc == 2) ? pv[g][q].z
                                       : pv[g][q].w;
            acc[g].x = fmaf(fa, pj, acc[g].x);
            acc[g].y = fmaf(fb, pj, acc[g].y);
            acc[g].z = fmaf(fc, pj, acc[g].z);
            acc[g].w = fmaf(fd, pj, acc[g].w);
          }
        }
    };

    int j = 0;
#pragma unroll 1
    for (int i = 0; i < fRowsG / (2 * fRows); ++i, j += 2 * fRows) {
      stage(buf0, buf1, j, j + fRows);
      stage(buf1, buf0, j + fRows, j + 2 * fRows);
    }

    if (grp != 0) {
#pragma unroll
      for (int g = 0; g < fG; ++g)
        *(float4*)&red_sh[grp - 1][g][d0] = acc[g];
    }
    __syncthreads();

    if (grp == 0) {
#pragma unroll
      for (int g = 0; g < fG; ++g) {
        float4 v = acc[g];
#pragma unroll
        for (int q = 0; q < fGroups - 1; ++q) {
          const float4 p = *(const float4*)&red_sh[q][g][d0];
          v.x += p.x; v.y += p.y; v.z += p.z; v.w += p.w;
        }
        v.x = fmaf(s[g], dv[g].x, v.x);
        v.y = fmaf(s[g], dv[g].y, v.y);
        v.z = fmaf(s[g], dv[g].z, v.z);
        v.w = fmaf(s[g], dv[g].w, v.w);
        r[g].x -= v.x; r[g].y -= v.y; r[g].z -= v.z; r[g].w -= v.w;
        const float rho = 1.0f / (two_sig1[g] - rho_prev[g]);
        const float c1 = rho * rho_prev[g];
        const float c2 = rho * two_over_delta;
        dv[g].x = fmaf(c1, dv[g].x, c2 * r[g].x);
        dv[g].y = fmaf(c1, dv[g].y, c2 * r[g].y);
        dv[g].z = fmaf(c1, dv[g].z, c2 * r[g].z);
        dv[g].w = fmaf(c1, dv[g].w, c2 * r[g].w);
        y[g].x += dv[g].x; y[g].y += dv[g].y;
        y[g].z += dv[g].z; y[g].w += dv[g].w;
        rho_prev[g] = rho;
        *(float4*)&d_sh[g][d0] = dv[g];
      }
    }
    __syncthreads();
  }

  if (grp == 0) {
#pragma unroll
    for (int g = 0; g < fG; ++g) {
      if (vld[g]) {
        float4 o;
        o.x = oscale[g] * y[g].x;
        o.y = oscale[g] * y[g].y;
        o.z = oscale[g] * y[g].z;
        o.w = oscale[g] * y[g].w;
        *(float4*)&out[(size_t)(b0 + g) * kD + d0] = o;
      }
    }
  }
}

extern "C" void kernel_launch(void* const* d_in, const int* in_sizes, int n_in,
                              void* d_out, int out_size, void* d_ws, size_t ws_size,
                              hipStream_t stream) {
  const float* x  = (const float*)d_in[0];   // [B, D] fp32
  const float* t  = (const float*)d_in[1];   // [B]    fp32
  const float* mu = (const float*)d_in[2];   // [D]    fp32
  const float* A  = (const float*)d_in[3];   // [D, D] fp32 SPD
  float* out = (float*)d_out;
  const int batch = in_sizes[1];

  char* ws = (char*)d_ws;
  const size_t flagBytes = 256u * kBarStride * sizeof(unsigned);  // 4 KB
  const size_t need = 1536 * 1024 + flagBytes;                    // = r14-proven

  if (batch == kD && ws_size >= need) {
    unsigned short* Abf  = (unsigned short*)(ws);                // 512 KB Abar
    unsigned short* A2bf = (unsigned short*)(ws + 512 * 1024);   // 512 KB Abar^2
    unsigned short* K2g  = (unsigned short*)(ws + 1024 * 1024);  // 512 KB K2
    unsigned* flags = (unsigned*)(ws + 1536 * 1024);             // 4 KB

    a_to_bf16_zs<<<kD * kD / 4 / 256, 256, 0, stream>>>(A, (unsigned*)Abf, flags);
    a2_gemm<<<256, 256, 0, stream>>>(Abf, A2bf);
    cheb_krylov<<<kGroupsC * kMembers, 256, 0, stream>>>(
        x, t, mu, Abf, A2bf, out, K2g, flags);
  } else {
    unsigned* Abf = (unsigned*)d_ws;
    a_to_bf16<<<(kD * kD / 4 + 255) / 256, 256, 0, stream>>>(A, Abf);
    const int blocks = (batch + fG - 1) / fG;
    vp_sde_cheb_fb<<<blocks, fThreads, 0, stream>>>(
        x, t, mu, (const uint2*)Abf, out, batch);
  }
}

// Round 15
// 71.922 us; speedup vs baseline: 1.0702x; 1.0702x over previous
//
#include <hip/hip_runtime.h>
#include <math.h>

namespace {
constexpr int kD = 512;
constexpr float kBetaMin = 0.1f;
constexpr float kBetaMax = 20.0f;
constexpr float kTMax = 1.0f;
// Spectrum of A = M M^T / D + I: lambda_min >= 1 (Wishart PSD),
// lambda_max ~ 4.96 (MP edge 4 + I + TW fluctuation). Containing bounds:
constexpr float kLamMin = 1.0f;
constexpr float kLamMax = 5.2f;
constexpr float kDelta = (kLamMax - kLamMin) * 0.5f;
// kSteps = matvec count. k=4 analytic truncation ~0.03-0.045 vs threshold
// 0.089; measured absmax sits at the bf16 floor (0.0156).
constexpr int kSteps = 4;

// r20: r18 structure with the prologue dispatch DELETED (ledger r14-r19:
// exchange-round count ~free (r19), exchange impl ~free (r18), A-streaming
// capped (r15/r17); the live levers are LAUNCH COUNT (+3-5us each) and the
// fixed in-region term). Each block converts ITS OWN 64 fp32 A-rows directly
// into LDS fragment order (same RNE -> bitwise-identical). Flag zeroing is
// replaced by BASE-RELATIVE monotonic flags: owner-only writes, all flags
// equal at kernel entry (constant fill poison, or uniform base+4 left by the
// previous replay); polls compare (flag - base) >= k in unsigned arithmetic.
// Main path = ONE kernel.
constexpr int kGroupsC = 32;     // independent groups (16 batch-columns each)
constexpr int kMembers = 8;      // blocks per group (64 A-rows each)
constexpr int kCPG = 16;         // columns per group
constexpr int kRowsB = 64;       // A-rows per block (held in LDS)
constexpr int kBarStride = 32;   // uints per flag -> own 128 B line
constexpr int kFragElems = kCPG * kD;   // 8192 bf16 = 16 KB per group D-block

typedef __attribute__((ext_vector_type(8))) short short8;   // 8 bf16
typedef __attribute__((ext_vector_type(4))) float float4v;  // 4 fp32 acc
}

__device__ inline unsigned short bf16_rne(float f) {
  unsigned u = __float_as_uint(f);
  u = (u + 0x7FFFu + ((u >> 16) & 1u)) >> 16;
  return (unsigned short)u;
}

__device__ inline unsigned pack_bf16_rne2(float a, float b) {
  unsigned ua = __float_as_uint(a), ub = __float_as_uint(b);
  ua = (ua + 0x7FFFu + ((ua >> 16) & 1u)) >> 16;
  ub = (ub + 0x7FFFu + ((ub >> 16) & 1u)) >> 16;
  return ua | (ub << 16);
}

// Coherence-bypassing 8 B accessors (relaxed agent-scope atomics ->
// global_{load,store}_dwordx2 sc0 sc1 through to the Infinity Cache —
// proven pattern from r10/r11/r14/r18).
__device__ inline void store8_agent(void* p, unsigned lo, unsigned hi) {
  const unsigned long long v = (unsigned long long)lo | ((unsigned long long)hi << 32);
  __hip_atomic_store((unsigned long long*)p, v, __ATOMIC_RELAXED,
                     __HIP_MEMORY_SCOPE_AGENT);
}
__device__ inline unsigned long long load8_agent(const void* p) {
  return __hip_atomic_load((const unsigned long long*)p, __ATOMIC_RELAXED,
                           __HIP_MEMORY_SCOPE_AGENT);
}

// ---------------- Single-kernel persistent-chain path (batch == 512) --------
// 256 blocks = 32 groups x 8 members. Group g owns batch columns [16g,16g+16);
// member m owns A rows [64m,64m+64), converted fp32->bf16 IN-KERNEL into LDS
// (MFMA-fragment order; same RNE as the old prologue -> bitwise-identical).
// Step: poll 8 member flags ((fl - base) >= k) -> gather 16 KB D to LDS ->
// stride-1 ds_read_b128 -> 16 MFMAs/wave -> recurrence -> publish 8 B
// fragment -> drain -> flag = base + k + 1.
__global__ __launch_bounds__(256) void cheb_fused(
    const float* __restrict__ x,    // [B, D]
    const float* __restrict__ t,    // [B]
    const float* __restrict__ mu,   // [D]
    const float* __restrict__ A,    // [D, D] fp32 row-major
    float* __restrict__ out,        // [B, D]
    unsigned short* __restrict__ Dt0,   // fragment-ordered ping (32 x 16 KB)
    unsigned short* __restrict__ Dt1,   // fragment-ordered pong
    unsigned* __restrict__ flags) {     // [256*kBarStride], NEVER zeroed
  const int group = blockIdx.x & (kGroupsC - 1);
  const int member = blockIdx.x >> 5;
  const int c0 = group * kCPG;
  const int i0 = member * kRowsB;
  const int tid = threadIdx.x;
  const int wave = tid >> 6;
  const int lane = tid & 63;
  const int quad = lane >> 4;
  const int lc = lane & 15;
  const int c = c0 + lc;                    // this thread's batch column
  const int ibase = i0 + wave * 16 + quad * 4;  // 4 consecutive k (=row) indices

  // Producer fragment address: slot = (k>>5)*64 + ((k>>3)&3)*16 + col,
  // elem = slot*8 + (k&7). Thread's k=ibase..ibase+3 -> one aligned 8 B piece.
  const size_t fragOff = (size_t)group * kFragElems +
      (size_t)(((ibase >> 5) * 64 + ((ibase >> 3) & 3) * 16 + lc) * 8 + (ibase & 7));

  // LDS: A slab 64 KB (fragment-ordered) + D staging 16 KB + 2 KB pad = 82 KB
  // -> 1 block/CU: dedicated L2 port, no co-resident straggler.
  __shared__ unsigned short As[kRowsB * kD];
  __shared__ unsigned short Ds[kFragElems + 1024];

  // --- base-relative flag: owner-only writes; all flags equal at entry ---
  unsigned* const myFlag = flags + ((group << 3) + member) * kBarStride;
  const unsigned base =
      __hip_atomic_load(myFlag, __ATOMIC_RELAXED, __HIP_MEMORY_SCOPE_AGENT);

  // --- per-column Chebyshev scalars (registers) ---
  const float tb = t[c];
  const float Bt = (kBetaMax - kBetaMin) / (2.0f * kTMax) * tb * tb + kBetaMin * tb;
  const float s_c = expm1f(Bt);
  const float eh = expf(0.5f * Bt);
  const float oscale = -eh * sqrtf(1.0f - expf(-Bt));
  const float theta = 0.5f * (kLamMin + kLamMax) + s_c;
  const float two_sig1 = 2.0f * theta / kDelta;
  const float c2base = 2.0f / kDelta;
  float rho_prev = kDelta / theta;          // 1/sigma1

  // --- state init + EARLY publish of D_1 (fragment-ordered 8 B store) ---
  float R[4], Dv[4], Y[4];
  {
    const float inv_theta = 1.0f / theta;
#pragma unroll
    for (int m = 0; m < 4; ++m) {
      const int i = ibase + m;
      const float b = eh * x[(size_t)c * kD + i] - mu[i];
      R[m] = b;
      Dv[m] = b * inv_theta;
      Y[m] = Dv[m];
    }
    store8_agent(Dt0 + fragOff,
                 (unsigned)bf16_rne(Dv[0]) | ((unsigned)bf16_rne(Dv[1]) << 16),
                 (unsigned)bf16_rne(Dv[2]) | ((unsigned)bf16_rne(Dv[3]) << 16));
  }

  // --- stage + CONVERT A slab: fp32 32 B coalesced reads -> bf16 fragment
  //     order (identical RNE to the old prologue -> bitwise-identical As) ---
  for (int idx = tid; idx < kRowsB * (kD / 8); idx += 256) {
    const int row = idx >> 6;              // local row 0..63
    const int col = (idx & 63) * 8;        // j-run start (j=0)
    const float* ap = A + (size_t)(i0 + row) * kD + col;
    const float4 fa = *(const float4*)(ap);
    const float4 fb = *(const float4*)(ap + 4);
    uint4 v;
    v.x = pack_bf16_rne2(fa.x, fa.y);
    v.y = pack_bf16_rne2(fa.z, fa.w);
    v.z = pack_bf16_rne2(fb.x, fb.y);
    v.w = pack_bf16_rne2(fb.z, fb.w);
    const int w = row >> 4, l = row & 15;
    const int kk = col >> 5, qd = (col >> 3) & 3;
    *(uint4*)&As[(w * 1024 + kk * 64 + qd * 16 + l) * 8] = v;
  }

  __syncthreads();   // drains vmcnt: D_1 publish + A staging complete
  if (tid == 0)
    __hip_atomic_store(myFlag, base + 1u, __ATOMIC_RELAXED,
                       __HIP_MEMORY_SCOPE_AGENT);

  const unsigned short* groupIn0 = Dt0 + (size_t)group * kFragElems;
  const unsigned short* groupIn1 = Dt1 + (size_t)group * kFragElems;

  for (int k = 1; k <= kSteps; ++k) {
    // ---- flag wait: threads 0..7 poll one member's flag each ----
    if (tid < kMembers) {
      const unsigned* fl = flags + ((group << 3) + tid) * kBarStride;
      while ((__hip_atomic_load(fl, __ATOMIC_RELAXED, __HIP_MEMORY_SCOPE_AGENT) -
              base) < (unsigned)k)
        __builtin_amdgcn_s_sleep(1);
    }
    __syncthreads();

    // ---- cooperative gather: group's 16 KB D-block -> LDS (coalesced) ----
    const unsigned short* gin = (k & 1) ? groupIn0 : groupIn1;
    unsigned long long stg[8];
#pragma unroll
    for (int i = 0; i < 8; ++i)
      stg[i] = load8_agent((const char*)gin + (size_t)i * 2048 + (size_t)tid * 8);
#pragma unroll
    for (int i = 0; i < 8; ++i)
      *(unsigned long long*)((char*)Ds + (size_t)i * 2048 + (size_t)tid * 8) = stg[i];
    __syncthreads();

    // ---- V-tile = A_slab x D (K = 512): B-frags from LDS, stride-1 b128 ----
    float4v acc = {0.f, 0.f, 0.f, 0.f};
    const unsigned short* afp = As + (size_t)(wave * 1024 + lane) * 8;
#pragma unroll
    for (int kk = 0; kk < kD / 32; ++kk) {
      const short8 af = *(const short8*)(afp + (size_t)kk * 64 * 8);
      const short8 bf = *(const short8*)(Ds + (size_t)(kk * 64 + lane) * 8);
      acc = __builtin_amdgcn_mfma_f32_16x16x32_bf16(af, bf, acc, 0, 0, 0);
    }

    // ---- Chebyshev recurrence (exact fp32 diagonal term s_c * D) ----
    const float rho_new = 1.0f / (two_sig1 - rho_prev);
    const float cc1 = rho_new * rho_prev;
    const float cc2 = rho_new * c2base;
#pragma unroll
    for (int m = 0; m < 4; ++m) {
      const float v = acc[m] + s_c * Dv[m];
      R[m] -= v;
      Dv[m] = fmaf(cc1, Dv[m], cc2 * R[m]);
      Y[m] += Dv[m];
    }
    rho_prev = rho_new;

    if (k < kSteps) {
      unsigned short* gout = ((k & 1) ? Dt1 : Dt0);
      store8_agent(gout + fragOff,
                   (unsigned)bf16_rne(Dv[0]) | ((unsigned)bf16_rne(Dv[1]) << 16),
                   (unsigned)bf16_rne(Dv[2]) | ((unsigned)bf16_rne(Dv[3]) << 16));
      __syncthreads();   // drains vmcnt: whole block's D_{k+1} publish complete
      if (tid == 0)
        __hip_atomic_store(myFlag, base + (unsigned)(k + 1), __ATOMIC_RELAXED,
                           __HIP_MEMORY_SCOPE_AGENT);
    } else {
      float4 o;
      o.x = oscale * Y[0];
      o.y = oscale * Y[1];
      o.z = oscale * Y[2];
      o.w = oscale * Y[3];
      *(float4*)(out + (size_t)c * kD + ibase) = o;
    }
  }
}

// ---------------- Fallback path (r6 kernel, any batch) ----------------
__global__ __launch_bounds__(256) void a_to_bf16(
    const float* __restrict__ A, unsigned* __restrict__ Abf) {
  const int i = blockIdx.x * 256 + threadIdx.x;
  const float4 f = ((const float4*)A)[i];
  uint2 u;
  u.x = pack_bf16_rne2(f.x, f.y);
  u.y = pack_bf16_rne2(f.z, f.w);
  ((uint2*)Abf)[i] = u;
}

namespace {
constexpr int fGroups = 8;
constexpr int fTPG = 128;
constexpr int fThreads = fGroups * fTPG;
constexpr int fRowsG = kD / fGroups;
constexpr int fG = 2;
constexpr int fDeg = 8;
constexpr int fRows = 8;
}

__global__ __launch_bounds__(fThreads) void vp_sde_cheb_fb(
    const float* __restrict__ x, const float* __restrict__ t,
    const float* __restrict__ mu, const uint2* __restrict__ Abf,
    float* __restrict__ out, int batch) {
  const int b0 = blockIdx.x * fG;
  const int tid = threadIdx.x;
  const int grp = tid >> 7;
  const int tl = tid & (fTPG - 1);
  const int d0 = 4 * tl;
  const int jbase = grp * fRowsG;

  __shared__ alignas(16) float d_sh[fG][kD];
  __shared__ alignas(16) float red_sh[fGroups - 1][fG][kD];

  float s[fG], two_sig1[fG], rho_prev[fG], oscale[fG];
  bool vld[fG];
  float4 y[fG], r[fG], dv[fG];
  const float two_over_delta = 2.0f / kDelta;

  uint2 buf0[fRows], buf1[fRows];
#pragma unroll
  for (int rr = 0; rr < fRows; ++rr)
    buf0[rr] = Abf[(size_t)(jbase + rr) * (kD / 4) + tl];

#pragma unroll
  for (int g = 0; g < fG; ++g) {
    const int b = b0 + g;
    vld[g] = (b < batch);
    const float tb = vld[g] ? t[b] : 1.0f;
    const float Bt = (kBetaMax - kBetaMin) / (2.0f * kTMax) * tb * tb + kBetaMin * tb;
    const float sg = expm1f(Bt);
    const float eh = expf(0.5f * Bt);
    s[g] = sg;
    oscale[g] = -eh * sqrtf(1.0f - expf(-Bt));
    const float theta = 0.5f * (kLamMin + kLamMax) + sg;
    const float sig1 = theta / kDelta;
    two_sig1[g] = 2.0f * sig1;
    rho_prev[g] = 1.0f / sig1;

    if (grp == 0) {
      float4 rv = {0.f, 0.f, 0.f, 0.f};
      if (vld[g]) {
        const float4 xv = *(const float4*)&x[(size_t)b * kD + d0];
        const float4 mu4 = *(const float4*)&mu[d0];
        rv.x = eh * xv.x - mu4.x;
        rv.y = eh * xv.y - mu4.y;
        rv.z = eh * xv.z - mu4.z;
        rv.w = eh * xv.w - mu4.w;
      }
      r[g] = rv;
      const float it = 1.0f / theta;
      dv[g].x = rv.x * it; dv[g].y = rv.y * it;
      dv[g].z = rv.z * it; dv[g].w = rv.w * it;
      y[g] = dv[g];
      *(float4*)&d_sh[g][d0] = dv[g];
    }
  }
  __syncthreads();

  for (int k = 1; k < fDeg; ++k) {
    float4 acc[fG];
#pragma unroll
    for (int g = 0; g < fG; ++g) acc[g] = {0.f, 0.f, 0.f, 0.f};

    auto stage = [&](uint2 (&cons)[fRows], uint2 (&ld)[fRows], int jc, int jl) {
#pragma unroll
      for (int rr = 0; rr < fRows; ++rr)
        ld[rr] = Abf[(size_t)(jbase + ((jl + rr) & (fRowsG - 1))) * (kD / 4) + tl];
      float4 pv[fG][fRows / 4];
#pragma unroll
      for (int g = 0; g < fG; ++g)
#pragma unroll
        for (int q = 0; q < fRows / 4; ++q)
          pv[g][q] = *(const float4*)&d_sh[g][jbase + jc + 4 * q];
#pragma unroll
      for (int q = 0; q < fRows / 4; ++q)
#pragma unroll
        for (int cc = 0; cc < 4; ++cc) {
          const uint2 u = cons[4 * q + cc];
          const float fa = __uint_as_float(u.x << 16);
          const float fb = __uint_as_float(u.x & 0xFFFF0000u);
          const float fc = __uint_as_float(u.y << 16);
          const float fd = __uint_as_float(u.y & 0xFFFF0000u);
#pragma unroll
          for (int g = 0; g < fG; ++g) {
            const float pj = (cc == 0) ? pv[g][q].x
                           : (cc == 1) ? pv[g][q].y
                           : (cc == 2) ? pv[g][q].z
                                       : pv[g][q].w;
            acc[g].x = fmaf(fa, pj, acc[g].x);
            acc[g].y = fmaf(fb, pj, acc[g].y);
            acc[g].z = fmaf(fc, pj, acc[g].z);
            acc[g].w = fmaf(fd, pj, acc[g].w);
          }
        }
    };

    int j = 0;
#pragma unroll 1
    for (int i = 0; i < fRowsG / (2 * fRows); ++i, j += 2 * fRows) {
      stage(buf0, buf1, j, j + fRows);
      stage(buf1, buf0, j + fRows, j + 2 * fRows);
    }

    if (grp != 0) {
#pragma unroll
      for (int g = 0; g < fG; ++g)
        *(float4*)&red_sh[grp - 1][g][d0] = acc[g];
    }
    __syncthreads();

    if (grp == 0) {
#pragma unroll
      for (int g = 0; g < fG; ++g) {
        float4 v = acc[g];
#pragma unroll
        for (int q = 0; q < fGroups - 1; ++q) {
          const float4 p = *(const float4*)&red_sh[q][g][d0];
          v.x += p.x; v.y += p.y; v.z += p.z; v.w += p.w;
        }
        v.x = fmaf(s[g], dv[g].x, v.x);
        v.y = fmaf(s[g], dv[g].y, v.y);
        v.z = fmaf(s[g], dv[g].z, v.z);
        v.w = fmaf(s[g], dv[g].w, v.w);
        r[g].x -= v.x; r[g].y -= v.y; r[g].z -= v.z; r[g].w -= v.w;
        const float rho = 1.0f / (two_sig1[g] - rho_prev[g]);
        const float c1 = rho * rho_prev[g];
        const float c2 = rho * two_over_delta;
        dv[g].x = fmaf(c1, dv[g].x, c2 * r[g].x);
        dv[g].y = fmaf(c1, dv[g].y, c2 * r[g].y);
        dv[g].z = fmaf(c1, dv[g].z, c2 * r[g].z);
        dv[g].w = fmaf(c1, dv[g].w, c2 * r[g].w);
        y[g].x += dv[g].x; y[g].y += dv[g].y;
        y[g].z += dv[g].z; y[g].w += dv[g].w;
        rho_prev[g] = rho;
        *(float4*)&d_sh[g][d0] = dv[g];
      }
    }
    __syncthreads();
  }

  if (grp == 0) {
#pragma unroll
    for (int g = 0; g < fG; ++g) {
      if (vld[g]) {
        float4 o;
        o.x = oscale[g] * y[g].x;
        o.y = oscale[g] * y[g].y;
        o.z = oscale[g] * y[g].z;
        o.w = oscale[g] * y[g].w;
        *(float4*)&out[(size_t)(b0 + g) * kD + d0] = o;
      }
    }
  }
}

extern "C" void kernel_launch(void* const* d_in, const int* in_sizes, int n_in,
                              void* d_out, int out_size, void* d_ws, size_t ws_size,
                              hipStream_t stream) {
  const float* x  = (const float*)d_in[0];   // [B, D] fp32
  const float* t  = (const float*)d_in[1];   // [B]    fp32
  const float* mu = (const float*)d_in[2];   // [D]    fp32
  const float* A  = (const float*)d_in[3];   // [D, D] fp32 SPD
  float* out = (float*)d_out;
  const int batch = in_sizes[1];

  char* ws = (char*)d_ws;
  const size_t flagBytes = 256u * kBarStride * sizeof(unsigned);  // 32 KB
  const size_t need = 1024 * 1024 + flagBytes;

  if (batch == kD && ws_size >= need) {
    unsigned short* Dt0 = (unsigned short*)(ws);                 // 512 KB ping
    unsigned short* Dt1 = (unsigned short*)(ws + 512 * 1024);    // 512 KB pong
    unsigned* flags = (unsigned*)(ws + 1024 * 1024);             // 32 KB

    // ONE dispatch on the main path: in-kernel A conversion + base-relative
    // flags (no prologue, no flag zeroing).
    cheb_fused<<<kGroupsC * kMembers, 256, 0, stream>>>(
        x, t, mu, A, out, Dt0, Dt1, flags);
  } else {
    unsigned* Abf = (unsigned*)d_ws;
    a_to_bf16<<<(kD * kD / 4 + 255) / 256, 256, 0, stream>>>(A, Abf);
    const int blocks = (batch + fG - 1) / fG;
    vp_sde_cheb_fb<<<blocks, fThreads, 0, stream>>>(
        x, t, mu, (const uint2*)Abf, out, batch);
  }
}